// Round 5
// baseline (316.892 us; speedup 1.0000x reference)
//
#include <hip/hip_runtime.h>
#include <stdint.h>

#define TSTEPS 256
#define NB 16
#define NM (TSTEPS*NB)   // 4096

typedef short s16x2 __attribute__((ext_vector_type(2)));

// perm(i) = bitrev8(gray(i)) : the Sobol value rng[i] = 2*perm(i)/256 - 1
__device__ __forceinline__ uint32_t perm8(int i) {
  uint32_t g = (uint32_t)(i ^ (i >> 1));
  return __brev(g) >> 24;
}

// y[m][n] = K + sum_k ashr16(a(m,k)*t(n,k) + e(m,k), 15)
//   x=1: a=+1, e=~p    (z = t-p-1,  ashr = pred-1)
//   x=0: a=-1, e=p'    (z = p'-t,   ashr = pred-1)
// 3 packed ops per 2 k-elements; shift amount 0x000F000F in VGPR (correct
// per-half VOP3P operand — inline consts are op_sel-trapped, see R1).
__device__ __forceinline__ void qstep3(uint32_t& acc, uint32_t t2, uint32_t a2,
                                       uint32_t e2, uint32_t c15) {
  uint32_t z;
  asm("v_pk_mad_i16 %0, %2, %3, %4\n\t"
      "v_pk_ashrrev_i16 %0, %5, %0\n\t"
      "v_pk_add_i16 %1, %1, %0"
      : "=&v"(z), "+v"(acc)
      : "v"(a2), "v"(t2), "v"(e2), "v"(c15));
}

__device__ __forceinline__ uint32_t pkadd16(uint32_t a, uint32_t b) {
  return __builtin_bit_cast(uint32_t,
        (s16x2)(__builtin_bit_cast(s16x2, a) + __builtin_bit_cast(s16x2, b)));
}

// unpack packed v16 (u | xbar<<15) pair -> (a2, e2)
__device__ __forceinline__ void unpackAE(uint32_t v2, uint32_t& a2, uint32_t& e2) {
  s16x2 sv = __builtin_bit_cast(s16x2, v2) >> 15;      // 0 / -1 per half (xbar)
  uint32_t su = __builtin_bit_cast(uint32_t, sv);
  uint32_t vand = v2 & 0x01FF01FFu;                    // u field
  e2 = pkadd16(~vand, su & 0x01FF01FFu);               // x=1: ~u ; x=0: 510-u = p'
  a2 = pkadd16(0x00010001u, pkadd16(su, su));          // +1 / -1
}

__device__ __forceinline__ int rank256(float w) {
  double v = 128.0 * (double)w + 128.0;
  int t = (int)ceil(v);
  if (t < 0) t = 0; if (t > 256) t = 256;
  return t;
}

// ----------------- weights -> rank tables (transposed [kp][n]) + rng, fused
__global__ __launch_bounds__(256) void k_wrank_all(
    const float* __restrict__ w1, const float* __restrict__ w2,
    const float* __restrict__ w3, float* __restrict__ rngf,
    uint32_t* __restrict__ T1t, uint32_t* __restrict__ T2t,
    uint32_t* __restrict__ T3t)
{
  int bid = blockIdx.x, tid = threadIdx.x;
  if (bid < 1024) {                      // w1 -> T1t [512 kp][512 n]
    int e = bid * 256 + tid;
    int n = e & 511, kp = e >> 9;
    int lo = rank256(w1[n * 1024 + 2 * kp]);
    int hi = rank256(w1[n * 1024 + 2 * kp + 1]);
    T1t[e] = (uint32_t)lo | ((uint32_t)hi << 16);
  } else if (bid < 1280) {               // w2 -> T2t [256 kp][256 n]
    int e = (bid - 1024) * 256 + tid;
    int n = e & 255, kp = e >> 8;
    int lo = rank256(w2[n * 512 + 2 * kp]);
    int hi = rank256(w2[n * 512 + 2 * kp + 1]);
    T2t[e] = (uint32_t)lo | ((uint32_t)hi << 16);
  } else if (bid < 1285) {               // w3 -> T3t [128 kp][10 n]
    int e = (bid - 1280) * 256 + tid;
    if (e < 1280) {
      int n = e % 10, kp = e / 10;
      int lo = rank256(w3[n * 256 + 2 * kp]);
      int hi = rank256(w3[n * 256 + 2 * kp + 1]);
      T3t[e] = (uint32_t)lo | ((uint32_t)hi << 16);
    }
  } else {
    int i = tid;
    unsigned g = i ^ (i >> 1);
    double x = 0.0, sc = 0.5;
    for (int j = 0; j < 8; ++j) { if ((g >> j) & 1u) x += sc; sc *= 0.5; }
    rngf[i] = (float)(x * 2.0 - 1.0);
  }
}

// ------------------------------------------------- layer-1 prefix (2 passes)
__global__ __launch_bounds__(256) void k_chunks(const int* __restrict__ x,
                                                uint16_t* __restrict__ cs) {
  int g = blockIdx.x * 256 + threadIdx.x;       // 131072
  int i = g & 1023, b = (g >> 10) & 15, c = g >> 14;
  int s = 0, t0 = c * 32;
  for (int tt = t0; tt < t0 + 32; ++tt) s += x[((size_t)tt * NB + b) * 1024 + i];
  cs[(c * NB + b) * 1024 + i] = (uint16_t)s;
}

// m-remap: m = b*256 + t  (b-major, so per-(b,o) t-runs are contiguous)
__global__ __launch_bounds__(256) void k_prep1(const int* __restrict__ x,
                                               const uint16_t* __restrict__ cs,
                                               uint16_t* __restrict__ V1) {
  int g = blockIdx.x * 256 + threadIdx.x;
  int i = g & 1023, b = (g >> 10) & 15, c = g >> 14;
  int cum = 0;
  for (int cc = 0; cc < c; ++cc) cum += cs[(cc * NB + b) * 1024 + i];
  int t0 = c * 32;
  for (int tt = t0; tt < t0 + 32; ++tt) {
    int m = b * 256 + tt;
    int xv = x[((size_t)tt * NB + b) * 1024 + i];
    int idx = xv ? cum : (tt - cum);
    uint32_t p = perm8(idx);
    uint32_t v = (xv ? p : (510u - p)) | ((uint32_t)(xv ^ 1) << 15);
    V1[(size_t)m * 1024 + i] = (uint16_t)v;
    cum += xv;
  }
}

// --------------------------------------------- packed-rank binary GEMM
// BM=64, BN=128, 256 thr, 4m x 8n per thread, split-K via blockIdx.z.
// V: u16 [4096][KD]. Tt: u32 [KD/2][NT]. Ypt: u16 [SK][NT][4096] (transposed).
template<int KD, int NT>
__global__ __launch_bounds__(256, 4) void k_bingemm(
    const uint16_t* __restrict__ V, const uint32_t* __restrict__ Tt,
    uint16_t* __restrict__ Ypt, int KC)
{
  __shared__ uint32_t UFs[64][68];   // [m][2*kp + {a2,e2}]
  __shared__ uint32_t Bs[32][132];   // [kp][n]
  const int tid = threadIdx.x;
  const int m0 = blockIdx.x * 64;
  const int n0 = blockIdx.y * 128;
  const int sk = blockIdx.z;
  const int k0 = sk * KC;
  const int tx = tid & 15;
  const int ty = tid >> 4;
  const uint32_t c15 = 0x000F000Fu;
  uint32_t acc[4][8] = {};
  for (int kt = 0; kt < KC; kt += 64) {
    const int kg = k0 + kt;
    { // stage V tile (64 rows x 64 k) -> (a2,e2) interleaved
      const int row = tid >> 2, part = tid & 3;
      const uint4* src = (const uint4*)(V + (size_t)(m0 + row) * KD + kg + part * 16);
      uint4 pa = src[0], pb = src[1];
      uint32_t w[8] = {pa.x, pa.y, pa.z, pa.w, pb.x, pb.y, pb.z, pb.w};
      uint32_t o[16];
      #pragma unroll
      for (int q = 0; q < 8; ++q) unpackAE(w[q], o[q * 2], o[q * 2 + 1]);
      #pragma unroll
      for (int q4 = 0; q4 < 4; ++q4)
        *(uint4*)&UFs[row][part * 16 + q4 * 4] =
            make_uint4(o[q4 * 4], o[q4 * 4 + 1], o[q4 * 4 + 2], o[q4 * 4 + 3]);
    }
    { // stage T tile (32 kp x 128 n) : straight copy
      const int kp8 = tid >> 3, seg = tid & 7;
      const uint4* src = (const uint4*)(Tt + ((size_t)(kg >> 1) + kp8) * NT + n0 + seg * 16);
      uint4 a = src[0], b = src[1], c = src[2], d = src[3];
      *(uint4*)&Bs[kp8][seg * 16]      = a;
      *(uint4*)&Bs[kp8][seg * 16 + 4]  = b;
      *(uint4*)&Bs[kp8][seg * 16 + 8]  = c;
      *(uint4*)&Bs[kp8][seg * 16 + 12] = d;
    }
    __syncthreads();
    #pragma unroll 4
    for (int kp2 = 0; kp2 < 16; ++kp2) {      // 2 kp per iter
      uint4 b0 = *(const uint4*)&Bs[2 * kp2][tx * 4];
      uint4 b1 = *(const uint4*)&Bs[2 * kp2][64 + tx * 4];
      uint4 b2 = *(const uint4*)&Bs[2 * kp2 + 1][tx * 4];
      uint4 b3 = *(const uint4*)&Bs[2 * kp2 + 1][64 + tx * 4];
      #pragma unroll
      for (int rr = 0; rr < 4; ++rr) {
        uint4 uf = *(const uint4*)&UFs[ty * 4 + rr][kp2 * 4]; // a2,e2,a2',e2'
        qstep3(acc[rr][0], b0.x, uf.x, uf.y, c15);
        qstep3(acc[rr][1], b0.y, uf.x, uf.y, c15);
        qstep3(acc[rr][2], b0.z, uf.x, uf.y, c15);
        qstep3(acc[rr][3], b0.w, uf.x, uf.y, c15);
        qstep3(acc[rr][4], b1.x, uf.x, uf.y, c15);
        qstep3(acc[rr][5], b1.y, uf.x, uf.y, c15);
        qstep3(acc[rr][6], b1.z, uf.x, uf.y, c15);
        qstep3(acc[rr][7], b1.w, uf.x, uf.y, c15);
        qstep3(acc[rr][0], b2.x, uf.z, uf.w, c15);
        qstep3(acc[rr][1], b2.y, uf.z, uf.w, c15);
        qstep3(acc[rr][2], b2.z, uf.z, uf.w, c15);
        qstep3(acc[rr][3], b2.w, uf.z, uf.w, c15);
        qstep3(acc[rr][4], b3.x, uf.z, uf.w, c15);
        qstep3(acc[rr][5], b3.y, uf.z, uf.w, c15);
        qstep3(acc[rr][6], b3.z, uf.z, uf.w, c15);
        qstep3(acc[rr][7], b3.w, uf.z, uf.w, c15);
      }
    }
    __syncthreads();
  }
  // transposed store: Ypt[sk][n][m], 4 consecutive m per store
  #pragma unroll
  for (int j = 0; j < 8; ++j) {
    int n = n0 + ((j < 4) ? (tx * 4 + j) : (64 + tx * 4 + j - 4));
    ushort4 v;
    v.x = (uint16_t)(KC + (short)(acc[0][j] & 0xFFFFu) + (short)(acc[0][j] >> 16));
    v.y = (uint16_t)(KC + (short)(acc[1][j] & 0xFFFFu) + (short)(acc[1][j] >> 16));
    v.z = (uint16_t)(KC + (short)(acc[2][j] & 0xFFFFu) + (short)(acc[2][j] >> 16));
    v.w = (uint16_t)(KC + (short)(acc[3][j] & 0xFFFFu) + (short)(acc[3][j] >> 16));
    *(ushort4*)(Ypt + ((size_t)sk * NT + n) * NM + m0 + ty * 4) = v;
  }
}

// ---------- scan (sum split-K partials + ulinear + ucompare) -> next V
template<int NOUT>
__global__ __launch_bounds__(64) void k_scan(
    const uint16_t* __restrict__ Ypt, const float* __restrict__ bias,
    const float* __restrict__ rngf, float offset,
    uint16_t* __restrict__ Vn, int SK)
{
  __shared__ float rs[256];
  int tid = threadIdx.x;
  for (int j = tid; j < 256; j += 64) rs[j] = rngf[j];
  __syncthreads();
  int g = blockIdx.x * 64 + tid;
  int o = g & (NOUT - 1);
  int b = g / NOUT;
  const uint16_t* row = Ypt + (size_t)o * NM + b * 256;
  const size_t pstr = (size_t)NOUT * NM;
  float bo = bias[o];
  float in_acc = 0.f, out_acc = 0.f, c = 0.f;
  int cum = 0;
  uint4 curq;
  {
    uint4 s = *(const uint4*)row;
    for (int sk = 1; sk < SK; ++sk) {
      uint4 q = *(const uint4*)(row + sk * pstr);
      s.x = pkadd16(s.x, q.x); s.y = pkadd16(s.y, q.y);
      s.z = pkadd16(s.z, q.z); s.w = pkadd16(s.w, q.w);
    }
    curq = s;
  }
  for (int t0 = 0; t0 < TSTEPS; t0 += 8) {
    uint4 nxtq = curq;
    if (t0 < 248) {
      uint4 s = *(const uint4*)(row + t0 + 8);
      for (int sk = 1; sk < SK; ++sk) {
        uint4 q = *(const uint4*)(row + sk * pstr + t0 + 8);
        s.x = pkadd16(s.x, q.x); s.y = pkadd16(s.y, q.y);
        s.z = pkadd16(s.z, q.z); s.w = pkadd16(s.w, q.w);
      }
      nxtq = s;
    }
    uint32_t cw[4] = {curq.x, curq.y, curq.z, curq.w};
    #pragma unroll
    for (int j = 0; j < 8; ++j) {
      int t = t0 + j;
      uint32_t cnt = (cw[j >> 1] >> ((j & 1) * 16)) & 0xFFFFu;
      float y = (float)cnt + ((bo > rs[t]) ? 1.f : 0.f);
      in_acc += y - offset;
      float outb = (in_acc > out_acc) ? 1.f : 0.f;
      out_acc += outb;
      float a = (c < 0.f) ? 1.f : outb;   // unary ReLU
      c += 2.f * a - 1.f;
      int xi = (int)a;
      int idx = xi ? cum : (t - cum);
      uint32_t p = perm8(idx);
      uint32_t v = (xi ? p : (510u - p)) | ((uint32_t)(xi ^ 1) << 15);
      Vn[(size_t)(b * 256 + t) * NOUT + o] = (uint16_t)v;
      cum += xi;
    }
    curq = nxtq;
  }
}

// ------------------------------------------------------------ layer 3 (OUT=10)
__global__ __launch_bounds__(256) void k_l3(
    const uint16_t* __restrict__ V3, const uint32_t* __restrict__ T3t,
    uint16_t* __restrict__ y3)
{
  __shared__ uint32_t T3s[128][16];    // [kp][o]
  __shared__ uint32_t UFs3[16][258];   // [m][2*kp + {a,e}]
  int tid = threadIdx.x;
  int m0 = blockIdx.x * 16;
  const uint32_t c15 = 0x000F000Fu;
  for (int j = tid; j < 2048; j += 256) {
    int kp = j >> 4, o2 = j & 15;
    T3s[kp][o2] = (o2 < 10) ? T3t[kp * 10 + o2] : 0u;
  }
  { int row = tid >> 4, part = tid & 15;
    const uint4* src = (const uint4*)(V3 + (size_t)(m0 + row) * 256 + part * 16);
    uint4 pa = src[0], pb = src[1];
    uint32_t w[8] = {pa.x, pa.y, pa.z, pa.w, pb.x, pb.y, pb.z, pb.w};
    uint32_t o[16];
    #pragma unroll
    for (int q = 0; q < 8; ++q) unpackAE(w[q], o[q * 2], o[q * 2 + 1]);
    #pragma unroll
    for (int q4 = 0; q4 < 4; ++q4)
      *(uint4*)&UFs3[row][part * 16 + q4 * 4] =
          make_uint4(o[q4 * 4], o[q4 * 4 + 1], o[q4 * 4 + 2], o[q4 * 4 + 3]);
  }
  __syncthreads();
  int mr = tid >> 4, o = tid & 15;
  uint32_t acc = 0;
  #pragma unroll 4
  for (int kp2 = 0; kp2 < 64; ++kp2) {
    uint4 uf = *(const uint4*)&UFs3[mr][kp2 * 4];
    qstep3(acc, T3s[2 * kp2][o],     uf.x, uf.y, c15);
    qstep3(acc, T3s[2 * kp2 + 1][o], uf.z, uf.w, c15);
  }
  if (o < 10)
    y3[(size_t)(m0 + mr) * 16 + o] =
        (uint16_t)(256 + (short)(acc & 0xFFFFu) + (short)(acc >> 16));
}

// ----------------------------------------------------- layer-3 scan -> z vals
__global__ __launch_bounds__(256) void k_scan3(
    const uint16_t* __restrict__ y3, const float* __restrict__ b3,
    const float* __restrict__ pred, const float* __restrict__ rngf,
    float* __restrict__ zbuf)
{
  __shared__ float rs[256];
  int tid = threadIdx.x;
  rs[tid] = rngf[tid];
  __syncthreads();
  int b = tid >> 4, o = tid & 15;
  bool act = (o < 10);
  float bo = act ? b3[o] : 0.f;
  float pr = act ? pred[b * 10 + o] : 0.f;
  float in_acc = 0.f, out_acc = 0.f;
  for (int t0 = 0; t0 < TSTEPS; t0 += 8) {
    uint16_t yv[8];
    #pragma unroll
    for (int j = 0; j < 8; ++j) yv[j] = y3[(size_t)(b * 256 + t0 + j) * 16 + o];
    #pragma unroll
    for (int j = 0; j < 8; ++j) {
      int t = t0 + j;
      float y = (float)yv[j] + ((bo > rs[t]) ? 1.f : 0.f);
      in_acc += y - 127.5f;
      float ob = (in_acc > out_acc) ? 1.f : 0.f;
      out_acc += ob;
      if (act) zbuf[(size_t)(t * NB + b) * 16 + o] = 2.f * ob - 1.f - pr;
    }
  }
}

// -------------------------------------------------------------- log_softmax
__global__ __launch_bounds__(256) void k_softmax(const float* __restrict__ zbuf,
                                                 float* __restrict__ out)
{
  int m = blockIdx.x * 256 + threadIdx.x;   // 4096, t-major
  float z[10], mx = -3e38f;
  #pragma unroll
  for (int o = 0; o < 10; ++o) { z[o] = zbuf[m * 16 + o]; mx = fmaxf(mx, z[o]); }
  float s = 0.f;
  #pragma unroll
  for (int o = 0; o < 10; ++o) s += expf(z[o] - mx);
  float ls = logf(s);
  #pragma unroll
  for (int o = 0; o < 10; ++o) out[m * 10 + o] = z[o] - mx - ls;
}

// ---------------------------------------------------------------------------
extern "C" void kernel_launch(void* const* d_in, const int* in_sizes, int n_in,
                              void* d_out, int out_size, void* d_ws, size_t ws_size,
                              hipStream_t stream) {
  (void)in_sizes; (void)n_in; (void)out_size;
  const float* w1   = (const float*)d_in[0];
  const float* b1   = (const float*)d_in[1];
  const float* w2   = (const float*)d_in[2];
  const float* b2   = (const float*)d_in[3];
  const float* w3   = (const float*)d_in[4];
  const float* b3   = (const float*)d_in[5];
  const float* pred = (const float*)d_in[6];
  const int*   x    = (const int*)d_in[7];
  float* out = (float*)d_out;
  uint8_t* W = (uint8_t*)d_ws;

  float*    rngf = (float*)   (W + 0);          //   1 KB
  uint32_t* T1t  = (uint32_t*)(W + 4096);       //   1 MB   [512 kp][512 n]
  uint32_t* T2t  = (uint32_t*)(W + 1052672);    // 256 KB   [256 kp][256 n]
  uint32_t* T3t  = (uint32_t*)(W + 1314816);    //   8 KB   [128 kp][10 n]
  uint16_t* chks = (uint16_t*)(W + 1323008);    // 256 KB
  uint16_t* V1   = (uint16_t*)(W + 1585152);    //   8 MB  [dead after gemm1]
  uint16_t* Yp1t = (uint16_t*)(W + 9973760);    // SK1*4MB [n][m] transposed
  // aliases inside dead V1 region:
  uint16_t* V3   = (uint16_t*)(W + 1585152);    //   2 MB
  uint16_t* Y3   = (uint16_t*)(W + 3682304);    // 128 KB
  float*    zbuf = (float*)   (W + 3813376);    // 256 KB

  int SK1, SK2;
  if      (ws_size >= 47722496u) { SK1 = 8; SK2 = 8; }  // peak ~45.5 MB
  else if (ws_size >= 30945280u) { SK1 = 4; SK2 = 4; }  // peak ~29.5 MB
  else if (ws_size >= 22556672u) { SK1 = 2; SK2 = 4; }  // peak ~21.5 MB
  else                           { SK1 = 1; SK2 = 2; }  // peak ~17.5 MB
  const int KC1 = 1024 / SK1, KC2 = 512 / SK2;
  uint16_t* V2   = (uint16_t*)(W + 9973760 + (size_t)SK1 * 4194304); // 4 MB
  uint16_t* Yp2t = Yp1t;   // SK2*2MB <= SK1*4MB

  hipLaunchKernelGGL(k_wrank_all, dim3(1286), dim3(256), 0, stream,
                     w1, w2, w3, rngf, T1t, T2t, T3t);
  hipLaunchKernelGGL(k_chunks, dim3(512), dim3(256), 0, stream, x, chks);
  hipLaunchKernelGGL(k_prep1,  dim3(512), dim3(256), 0, stream, x, chks, V1);
  hipLaunchKernelGGL((k_bingemm<1024, 512>), dim3(64, 4, SK1), dim3(256), 0, stream,
                     V1, T1t, Yp1t, KC1);
  hipLaunchKernelGGL(k_scan<512>, dim3(128), dim3(64), 0, stream,
                     Yp1t, b1, rngf, 511.5f, V2, SK1);
  hipLaunchKernelGGL((k_bingemm<512, 256>), dim3(64, 2, SK2), dim3(256), 0, stream,
                     V2, T2t, Yp2t, KC2);
  hipLaunchKernelGGL(k_scan<256>, dim3(64), dim3(64), 0, stream,
                     Yp2t, b2, rngf, 255.5f, V3, SK2);
  hipLaunchKernelGGL(k_l3,     dim3(256), dim3(256), 0, stream, V3, T3t, Y3);
  hipLaunchKernelGGL(k_scan3,  dim3(1),   dim3(256), 0, stream, Y3, b3, pred, rngf, zbuf);
  hipLaunchKernelGGL(k_softmax, dim3(16), dim3(256), 0, stream, zbuf, out);
}

// Round 6
// 247.016 us; speedup vs baseline: 1.2829x; 1.2829x over previous
//
#include <hip/hip_runtime.h>
#include <stdint.h>

#define TSTEPS 256
#define NB 16
#define NM (TSTEPS*NB)   // 4096

typedef short s16x2 __attribute__((ext_vector_type(2)));

// perm(i) = bitrev8(gray(i)) : the Sobol value rng[i] = 2*perm8(i)/256 - 1
__device__ __forceinline__ uint32_t perm8(int i) {
  uint32_t g = (uint32_t)(i ^ (i >> 1));
  return __brev(g) >> 24;
}

// y = K + sum ashr16(a*t + e, 15) ; 3 packed ops per 2 k-elements.
__device__ __forceinline__ void qstep3(uint32_t& acc, uint32_t t2, uint32_t a2,
                                       uint32_t e2, uint32_t c15) {
  uint32_t z;
  asm("v_pk_mad_i16 %0, %2, %3, %4\n\t"
      "v_pk_ashrrev_i16 %0, %5, %0\n\t"
      "v_pk_add_i16 %1, %1, %0"
      : "=&v"(z), "+v"(acc)
      : "v"(a2), "v"(t2), "v"(e2), "v"(c15));
}

__device__ __forceinline__ uint32_t pkadd16(uint32_t a, uint32_t b) {
  return __builtin_bit_cast(uint32_t,
        (s16x2)(__builtin_bit_cast(s16x2, a) + __builtin_bit_cast(s16x2, b)));
}

// unpack packed v16 (u | xbar<<15) pair -> (a2, e2)
__device__ __forceinline__ void unpackAE(uint32_t v2, uint32_t& a2, uint32_t& e2) {
  s16x2 sv = __builtin_bit_cast(s16x2, v2) >> 15;      // 0 / -1 per half (xbar)
  uint32_t su = __builtin_bit_cast(uint32_t, sv);
  uint32_t vand = v2 & 0x01FF01FFu;
  e2 = pkadd16(~vand, su & 0x01FF01FFu);   // x=1: ~u ; x=0: 511-(u+1)+... = p'
  a2 = pkadd16(0x00010001u, pkadd16(su, su));          // +1 / -1
}

__device__ __forceinline__ int rank256(float w) {
  double v = 128.0 * (double)w + 128.0;
  int t = (int)ceil(v);
  if (t < 0) t = 0; if (t > 256) t = 256;
  return t;
}

// ----------------- fused prep: rank tables + bias bitmasks + x chunk sums
__global__ __launch_bounds__(256) void k_prepA(
    const float* __restrict__ w1, const float* __restrict__ w2,
    const float* __restrict__ w3, const float* __restrict__ b1,
    const float* __restrict__ b2, const float* __restrict__ b3,
    const int* __restrict__ x,
    uint32_t* __restrict__ T1t, uint32_t* __restrict__ T2t,
    uint32_t* __restrict__ T3t, uint32_t* __restrict__ bb1,
    uint32_t* __restrict__ bb2, uint32_t* __restrict__ bb3,
    uint16_t* __restrict__ cs)
{
  int bid = blockIdx.x, tid = threadIdx.x;
  if (bid < 1024) {                      // w1 -> T1t [512 kp][512 n]
    int e = bid * 256 + tid;
    int n = e & 511, kp = e >> 9;
    T1t[e] = (uint32_t)rank256(w1[n * 1024 + 2 * kp]) |
             ((uint32_t)rank256(w1[n * 1024 + 2 * kp + 1]) << 16);
  } else if (bid < 1280) {               // w2 -> T2t [256 kp][256 n]
    int e = (bid - 1024) * 256 + tid;
    int n = e & 255, kp = e >> 8;
    T2t[e] = (uint32_t)rank256(w2[n * 512 + 2 * kp]) |
             ((uint32_t)rank256(w2[n * 512 + 2 * kp + 1]) << 16);
  } else if (bid < 1285) {               // w3 -> T3t [128 kp][10 n]
    int e = (bid - 1280) * 256 + tid;
    if (e < 1280) {
      int n = e % 10, kp = e / 10;
      T3t[e] = (uint32_t)rank256(w3[n * 256 + 2 * kp]) |
               ((uint32_t)rank256(w3[n * 256 + 2 * kp + 1]) << 16);
    }
  } else if (bid < 1301) {               // bb1: 512 o x 8 words
    int w = (bid - 1285) * 256 + tid;
    int o = w >> 3, j = w & 7;
    double bv = (double)b1[o] * 128.0 + 128.0;
    uint32_t bits = 0;
    for (int s = 0; s < 32; ++s)
      if (bv > (double)perm8(j * 32 + s)) bits |= 1u << s;
    bb1[w] = bits;
  } else if (bid < 1309) {               // bb2: 256 o x 8 words
    int w = (bid - 1301) * 256 + tid;
    int o = w >> 3, j = w & 7;
    double bv = (double)b2[o] * 128.0 + 128.0;
    uint32_t bits = 0;
    for (int s = 0; s < 32; ++s)
      if (bv > (double)perm8(j * 32 + s)) bits |= 1u << s;
    bb2[w] = bits;
  } else if (bid == 1309) {              // bb3: 10 o x 8 words
    if (tid < 80) {
      int o = tid >> 3, j = tid & 7;
      double bv = (double)b3[o] * 128.0 + 128.0;
      uint32_t bits = 0;
      for (int s = 0; s < 32; ++s)
        if (bv > (double)perm8(j * 32 + s)) bits |= 1u << s;
      bb3[tid] = bits;
    }
  } else {                               // x chunk sums (512 blocks)
    int g = (bid - 1310) * 256 + tid;
    int i = g & 1023, b = (g >> 10) & 15, c = g >> 14;
    int s = 0, t0 = c * 32;
    for (int tt = t0; tt < t0 + 32; ++tt)
      s += x[((size_t)tt * NB + b) * 1024 + i];
    cs[(c * NB + b) * 1024 + i] = (uint16_t)s;
  }
}

// -------------------------------- layer-1 V build (m = b*256+t, b-major)
__global__ __launch_bounds__(256) void k_prep1(const int* __restrict__ x,
                                               const uint16_t* __restrict__ cs,
                                               uint16_t* __restrict__ V1) {
  int g = blockIdx.x * 256 + threadIdx.x;
  int i = g & 1023, b = (g >> 10) & 15, c = g >> 14;
  int cum = 0;
  for (int cc = 0; cc < c; ++cc) cum += cs[(cc * NB + b) * 1024 + i];
  int t0 = c * 32;
  for (int tt = t0; tt < t0 + 32; ++tt) {
    int m = b * 256 + tt;
    int xv = x[((size_t)tt * NB + b) * 1024 + i];
    int idx = xv ? cum : (tt - cum);
    uint32_t p = perm8(idx);
    V1[(size_t)m * 1024 + i] =
        (uint16_t)((xv ? p : (510u - p)) | ((uint32_t)(xv ^ 1) << 15));
    cum += xv;
  }
}

// ---------------- register-resident binary GEMM, broadcast-T, split-K
// m = blockIdx.x*256 + tid (one m per thread, U in regs for KC k's);
// n serial over NPB with T row read at wave-uniform LDS address (broadcast);
// partials u8: Yp[sk][n][m], value = exact count over this KC chunk.
template<int KD, int NT, int NPB, int KC>
__global__ __launch_bounds__(256) void k_gemmv2(
    const uint16_t* __restrict__ V, const uint32_t* __restrict__ Tt,
    uint8_t* __restrict__ Yp)
{
  constexpr int KP = KC / 2;
  constexpr int KROW = KP + 4;               // pad: row stride 16B-aligned
  __shared__ uint32_t Ts[NPB * KROW];
  const int tid = threadIdx.x;
  const int m = blockIdx.x * 256 + tid;
  const int n0 = blockIdx.y * NPB;
  const int sk = blockIdx.z;
  const int k0 = sk * KC;
  // stage T tile [NPB][KP] (transposed from Tt [kp][n])
  for (int w = tid; w < NPB * KP; w += 256) {
    int n = w & (NPB - 1), kp = w / NPB;
    Ts[n * KROW + kp] = Tt[((size_t)(k0 >> 1) + kp) * NT + n0 + n];
  }
  // U (a2,e2) into registers
  uint32_t a2[KP], e2[KP];
  {
    const uint4* src = (const uint4*)(V + (size_t)m * KD + k0);
    #pragma unroll
    for (int q = 0; q < KC / 8; ++q) {
      uint4 vv = src[q];
      unpackAE(vv.x, a2[q * 4 + 0], e2[q * 4 + 0]);
      unpackAE(vv.y, a2[q * 4 + 1], e2[q * 4 + 1]);
      unpackAE(vv.z, a2[q * 4 + 2], e2[q * 4 + 2]);
      unpackAE(vv.w, a2[q * 4 + 3], e2[q * 4 + 3]);
    }
  }
  __syncthreads();
  const uint32_t c15 = 0x000F000Fu;
  uint8_t* outp = Yp + ((size_t)sk * NT + n0) * (size_t)NM + m;
  #pragma unroll 2
  for (int n = 0; n < NPB; ++n) {
    const uint32_t* tr = &Ts[n * KROW];
    uint32_t q0 = 0, q1 = 0, q2 = 0, q3 = 0;
    #pragma unroll
    for (int j = 0; j < KP / 4; ++j) {
      uint4 tw = *(const uint4*)(tr + j * 4);   // wave-uniform -> broadcast
      qstep3(q0, tw.x, a2[j * 4 + 0], e2[j * 4 + 0], c15);
      qstep3(q1, tw.y, a2[j * 4 + 1], e2[j * 4 + 1], c15);
      qstep3(q2, tw.z, a2[j * 4 + 2], e2[j * 4 + 2], c15);
      qstep3(q3, tw.w, a2[j * 4 + 3], e2[j * 4 + 3], c15);
    }
    uint32_t s = pkadd16(pkadd16(q0, q1), pkadd16(q2, q3));
    int cnt = KC + (int)(short)(s & 0xFFFFu) + (int)(short)(s >> 16);
    outp[(size_t)n * NM] = (uint8_t)cnt;      // exact count in [0, KC]
  }
}

// ------------------- sum 16 u8 split-K planes -> u16 counts [n][m]
__global__ __launch_bounds__(256) void k_sumY(
    const uint8_t* __restrict__ Yp, uint16_t* __restrict__ Ys,
    int nwords, size_t plane_words)
{
  int i = blockIdx.x * 256 + threadIdx.x;
  if (i >= nwords) return;
  const uint32_t* p = (const uint32_t*)Yp;
  uint32_t aL = 0, aH = 0;
  for (int s = 0; s < 16; ++s) {
    uint32_t w = p[(size_t)s * plane_words + i];
    aL = pkadd16(aL, w & 0x00FF00FFu);
    aH = pkadd16(aH, (w >> 8) & 0x00FF00FFu);
  }
  uint2 o;
  o.x = (aL & 0xFFFFu) | (aH << 16);
  o.y = (aL >> 16) | (aH & 0xFFFF0000u);
  ((uint2*)Ys)[i] = o;
}

// ---------------- integer scan (ulinear + ucompare) -> next-layer V
// state x2 ints: in2=2*in_acc, out2=2*out_acc, c2=2*c — exact.
template<int NOUT, int OFF2, int LOGN>
__global__ __launch_bounds__(64) void k_scanv2(
    const uint16_t* __restrict__ Ys, const uint32_t* __restrict__ bb,
    uint16_t* __restrict__ Vn)
{
  int g = blockIdx.x * 64 + threadIdx.x;
  int o = g & (NOUT - 1);
  int b = g >> LOGN;
  const uint16_t* row = Ys + (size_t)o * NM + b * 256;
  int in2 = 0, out2 = 0, c2 = 0, cum = 0;
  uint4 cur = *(const uint4*)row;
  #pragma unroll
  for (int w = 0; w < 8; ++w) {
    uint32_t bwc = bb[o * 8 + w];
    #pragma unroll
    for (int cchunk = 0; cchunk < 4; ++cchunk) {
      int t0 = w * 32 + cchunk * 8;
      uint4 nxt = cur;
      if (t0 < 248) nxt = *(const uint4*)(row + t0 + 8);
      uint32_t cw[4] = {cur.x, cur.y, cur.z, cur.w};
      #pragma unroll
      for (int j = 0; j < 8; ++j) {
        int t = t0 + j;
        int cnt = (int)((cw[j >> 1] >> ((j & 1) * 16)) & 0xFFFFu);
        int bit = (int)((bwc >> (t & 31)) & 1u);
        in2 += 2 * cnt + 2 * bit - OFF2;
        int outb = (in2 > out2) ? 1 : 0;
        out2 += outb << 1;
        int a = (c2 < 0) ? 1 : outb;
        c2 += (a << 2) - 2;
        int idx = a ? cum : (t - cum);
        cum += a;
        uint32_t p = perm8(idx);
        Vn[(size_t)(b * 256 + t) * NOUT + o] =
            (uint16_t)((a ? p : (510u - p)) | ((uint32_t)(a ^ 1) << 15));
      }
      cur = nxt;
    }
  }
}

// ------------------------------------------------------------ layer 3 (OUT=10)
__global__ __launch_bounds__(256) void k_l3(
    const uint16_t* __restrict__ V3, const uint32_t* __restrict__ T3t,
    uint16_t* __restrict__ y3)
{
  __shared__ uint32_t T3s[128][16];    // [kp][o]
  __shared__ uint32_t UFs3[16][258];   // [m][2*kp + {a,e}]
  int tid = threadIdx.x;
  int m0 = blockIdx.x * 16;
  const uint32_t c15 = 0x000F000Fu;
  for (int j = tid; j < 2048; j += 256) {
    int kp = j >> 4, o2 = j & 15;
    T3s[kp][o2] = (o2 < 10) ? T3t[kp * 10 + o2] : 0u;
  }
  { int row = tid >> 4, part = tid & 15;
    const uint4* src = (const uint4*)(V3 + (size_t)(m0 + row) * 256 + part * 16);
    uint4 pa = src[0], pb = src[1];
    uint32_t w[8] = {pa.x, pa.y, pa.z, pa.w, pb.x, pb.y, pb.z, pb.w};
    uint32_t o[16];
    #pragma unroll
    for (int q = 0; q < 8; ++q) unpackAE(w[q], o[q * 2], o[q * 2 + 1]);
    #pragma unroll
    for (int q4 = 0; q4 < 4; ++q4)
      *(uint4*)&UFs3[row][part * 16 + q4 * 4] =
          make_uint4(o[q4 * 4], o[q4 * 4 + 1], o[q4 * 4 + 2], o[q4 * 4 + 3]);
  }
  __syncthreads();
  int mr = tid >> 4, o = tid & 15;
  uint32_t acc = 0;
  #pragma unroll 4
  for (int kp2 = 0; kp2 < 64; ++kp2) {
    uint4 uf = *(const uint4*)&UFs3[mr][kp2 * 4];
    qstep3(acc, T3s[2 * kp2][o],     uf.x, uf.y, c15);
    qstep3(acc, T3s[2 * kp2 + 1][o], uf.z, uf.w, c15);
  }
  if (o < 10)
    y3[(size_t)(m0 + mr) * 16 + o] =
        (uint16_t)(256 + (short)(acc & 0xFFFFu) + (short)(acc >> 16));
}

// ---------------- layer-3 scan (bit-matrix in LDS) + log_softmax, fused
__global__ __launch_bounds__(256) void k_scan3sm(
    const uint16_t* __restrict__ y3, const uint32_t* __restrict__ bb3,
    const float* __restrict__ pred, float* __restrict__ out)
{
  __shared__ uint32_t obl[16][16][8];
  __shared__ float prs[160];
  int tid = threadIdx.x;
  if (tid < 160) prs[tid] = pred[tid];
  int b = tid >> 4, o = tid & 15;
  if (o < 10) {
    const uint16_t* row = y3 + (size_t)b * 256 * 16 + o;
    int in2 = 0, out2 = 0;
    #pragma unroll
    for (int w = 0; w < 8; ++w) {
      uint32_t bwc = bb3[o * 8 + w];
      uint32_t bits = 0;
      for (int s = 0; s < 32; ++s) {
        int cnt = row[(w * 32 + s) * 16];
        in2 += 2 * cnt + 2 * (int)((bwc >> s) & 1u) - 255;
        int outb = (in2 > out2) ? 1 : 0;
        out2 += outb << 1;
        bits |= (uint32_t)outb << s;
      }
      obl[b][o][w] = bits;
    }
  }
  __syncthreads();
  for (int r = tid; r < 4096; r += 256) {
    int t = r >> 4, b2 = r & 15;
    float z[10], mx = -3e38f;
    #pragma unroll
    for (int oo = 0; oo < 10; ++oo) {
      int bit = (obl[b2][oo][t >> 5] >> (t & 31)) & 1;
      z[oo] = (bit ? 1.f : -1.f) - prs[b2 * 10 + oo];
      mx = fmaxf(mx, z[oo]);
    }
    float s = 0.f;
    #pragma unroll
    for (int oo = 0; oo < 10; ++oo) s += expf(z[oo] - mx);
    float ls = logf(s);
    float* op = out + (size_t)r * 10;       // r = t*16+b  ==  (t*NB+b)
    #pragma unroll
    for (int oo = 0; oo < 10; ++oo) op[oo] = z[oo] - mx - ls;
  }
}

// ---------------------------------------------------------------------------
extern "C" void kernel_launch(void* const* d_in, const int* in_sizes, int n_in,
                              void* d_out, int out_size, void* d_ws, size_t ws_size,
                              hipStream_t stream) {
  (void)in_sizes; (void)n_in; (void)out_size; (void)ws_size;
  const float* w1   = (const float*)d_in[0];
  const float* b1   = (const float*)d_in[1];
  const float* w2   = (const float*)d_in[2];
  const float* b2   = (const float*)d_in[3];
  const float* w3   = (const float*)d_in[4];
  const float* b3   = (const float*)d_in[5];
  const float* pred = (const float*)d_in[6];
  const int*   x    = (const int*)d_in[7];
  float* out = (float*)d_out;
  uint8_t* W = (uint8_t*)d_ws;

  uint32_t* T1t  = (uint32_t*)(W + 0);          // 1 MB  [512 kp][512 n]
  uint32_t* T2t  = (uint32_t*)(W + 1048576);    // 256 KB [256 kp][256 n]
  uint32_t* T3t  = (uint32_t*)(W + 1310720);    // 8 KB  [128 kp][10 n]
  uint32_t* bb1  = (uint32_t*)(W + 1318912);    // 16 KB
  uint32_t* bb2  = (uint32_t*)(W + 1335296);    // 8 KB
  uint32_t* bb3  = (uint32_t*)(W + 1343488);    // 512 B
  uint16_t* chks = (uint16_t*)(W + 1344000);    // 256 KB          end 1606144
  // V1 region (8 MB), dead after gemm1:
  uint16_t* V1   = (uint16_t*)(W + 1606144);
  uint16_t* Ys1  = (uint16_t*)(W + 1606144);    // 4 MB (alias, after gemm1)
  uint16_t* V2   = (uint16_t*)(W + 5800448);    // 4 MB
  // Yp region (33.55 MB):
  uint8_t*  Yp1  = (uint8_t*) (W + 9994752);    // 16 x 2 MB u8
  uint8_t*  Yp2  = (uint8_t*) (W + 9994752);    // 16 x 1 MB u8 (alias)
  uint16_t* Ys2  = (uint16_t*)(W + 26771968);   // 2 MB
  uint16_t* V3   = (uint16_t*)(W + 28869120);   // 2 MB
  uint16_t* Y3   = (uint16_t*)(W + 30966272);   // 128 KB
  // peak end = 43,549,184 bytes (proven available: R5 ran the 47.7 MB tier)

  hipLaunchKernelGGL(k_prepA, dim3(1822), dim3(256), 0, stream,
                     w1, w2, w3, b1, b2, b3, x, T1t, T2t, T3t, bb1, bb2, bb3, chks);
  hipLaunchKernelGGL(k_prep1, dim3(512), dim3(256), 0, stream, x, chks, V1);
  hipLaunchKernelGGL((k_gemmv2<1024, 512, 256, 64>), dim3(16, 2, 16), dim3(256),
                     0, stream, V1, T1t, Yp1);
  hipLaunchKernelGGL(k_sumY, dim3(2048), dim3(256), 0, stream,
                     Yp1, Ys1, 512 * NM / 4, (size_t)(512 * NM / 4));
  hipLaunchKernelGGL((k_scanv2<512, 1023, 9>), dim3(128), dim3(64), 0, stream,
                     Ys1, bb1, V2);
  hipLaunchKernelGGL((k_gemmv2<512, 256, 128, 32>), dim3(16, 2, 16), dim3(256),
                     0, stream, V2, T2t, Yp2);
  hipLaunchKernelGGL(k_sumY, dim3(1024), dim3(256), 0, stream,
                     Yp2, Ys2, 256 * NM / 4, (size_t)(256 * NM / 4));
  hipLaunchKernelGGL((k_scanv2<256, 511, 8>), dim3(64), dim3(64), 0, stream,
                     Ys2, bb2, V3);
  hipLaunchKernelGGL(k_l3, dim3(256), dim3(256), 0, stream, V3, T3t, Y3);
  hipLaunchKernelGGL(k_scan3sm, dim3(1), dim3(256), 0, stream, Y3, bb3, pred, out);
}